// Round 10
// baseline (885.364 us; speedup 1.0000x reference)
//
#include <hip/hip_runtime.h>

// HPCrnn R10: R8 (best: 618us) + dual-tile per wave. Diagnosis from R7/R9:
// latency-bound, not VALU-bound (VALU diet lowered VALUBusy 78->61% but dur
// ROSE). Fix: each wave owns TWO independent 16-row tiles sharing the same
// weight registers -> 2 independent MFMA chains + 2 independent epilogue
// chains per phase (fills latency stalls), and per-CU barrier-phase count
// halves (4 generations x 196 -> 2 x 196). Epilogue kept in R8's exact
// (measured-best) scalar exp/rcp form. 32 rows/block, grid 1024, 2 blocks/CU.

typedef int   i32x4 __attribute__((ext_vector_type(4)));
typedef float f32x4 __attribute__((ext_vector_type(4)));

// ---------- pre 1: basal tables + zero scale slots ----------
__global__ void basal2_kernel(const float* __restrict__ Wbasal,
                              const float* __restrict__ bias,
                              float* __restrict__ Atab, float* __restrict__ Etab,
                              float* __restrict__ ctab, int* __restrict__ scaleWS) {
    const int t = blockIdx.x, n = threadIdx.x;
    __shared__ float ca3s[256], red[256];
    const float x = (float)(t + 1);
    const float c0 = (float)n * (100.0f / 255.0f);
    const float d = (x - c0) * 0.2f;
    ca3s[n] = expf(-0.5f * d * d);
    __syncthreads();
    float bas = 0.f;
    #pragma unroll 8
    for (int k = 0; k < 256; ++k) bas += ca3s[k] * Wbasal[k * 256 + n];
    red[n] = bas;
    __syncthreads();
    for (int s = 128; s > 0; s >>= 1) {
        if (n < s) red[n] = fmaxf(red[n], red[n + s]);
        __syncthreads();
    }
    const float bmax = red[0];
    const float cq = 126.0f / (2.0f * bmax);   // headroom so q(ca1) < 127.5
    Atab[t * 256 + n] = bas * cq;
    Etab[t * 256 + n] = (bas - bias[n]) * cq + 0.5f;   // +0.5 folds rounding
    if (n == 0) ctab[t] = (2.0f * bmax) / 126.0f;
    if (t == 0 && n < 2) scaleWS[n] = 0;
}

// ---------- pre 2: weight absmax ----------
__global__ void wmax_kernel(const float* __restrict__ Wap, const float* __restrict__ Wc,
                            int* __restrict__ scaleWS) {
    const int i = blockIdx.x * 256 + threadIdx.x;
    float m1 = fabsf(Wap[i]);
    float m2 = fabsf(Wc[i]);
    #pragma unroll
    for (int o = 1; o < 64; o <<= 1) {
        m1 = fmaxf(m1, __shfl_xor(m1, o));
        m2 = fmaxf(m2, __shfl_xor(m2, o));
    }
    __shared__ float r1[4], r2[4];
    const int wv = threadIdx.x >> 6, ln = threadIdx.x & 63;
    if (ln == 0) { r1[wv] = m1; r2[wv] = m2; }
    __syncthreads();
    if (threadIdx.x == 0) {
        const float a = fmaxf(fmaxf(r1[0], r1[1]), fmaxf(r1[2], r1[3]));
        const float b = fmaxf(fmaxf(r2[0], r2[1]), fmaxf(r2[2], r2[3]));
        atomicMax(&scaleWS[0], __float_as_int(a));
        atomicMax(&scaleWS[1], __float_as_int(b));
    }
}

// ---------- pre 3: quantize weights to i8, transposed to [m][k] ----------
__global__ void wquant_kernel(const float* __restrict__ Wap, const float* __restrict__ Wc,
                              const int* __restrict__ scaleWS,
                              char* __restrict__ qWap, char* __restrict__ qWc) {
    const int m = blockIdx.x, k = threadIdx.x;
    const float q1 = 127.0f / __int_as_float(scaleWS[0]);
    const float q2 = 127.0f / __int_as_float(scaleWS[1]);
    qWap[m * 256 + k] = (char)(int)rintf(Wap[k * 256 + m] * q1);
    qWc[m * 256 + k]  = (char)(int)rintf(Wc[k * 256 + m] * q2);
}

// ---------- main: 32 rows/block (2 tiles/wave), 8 waves, 2 barriers/step ----------
__global__ __launch_bounds__(512, 4) void rnn_kernel(
    const float* __restrict__ cue, const float* __restrict__ ec5_init,
    const char* __restrict__ qWap, const char* __restrict__ qWc,
    const int* __restrict__ scaleWS, const float* __restrict__ Wact,
    const float* __restrict__ Atab, const float* __restrict__ Etab,
    const float* __restrict__ ctab, float* __restrict__ out)
{
    __shared__ __align__(16) char sStage[16384 + 2048];  // EA@0 CA@4096 EB@8192 CB@12288
    float* sPart = (float*)&sStage[16384];               // [tile*16+L][a][wave]

    const int tid  = threadIdx.x;
    const int wave = tid >> 6;
    const int lane = tid & 63;
    const int quad = lane >> 4;
    const int L    = lane & 15;
    const int wb   = wave * 32;
    const int row0 = blockIdx.x * 32;   // tile A rows row0+L, tile B rows row0+16+L

    const float sW1 = __int_as_float(scaleWS[0]);
    const float sW2 = __int_as_float(scaleWS[1]);
    const float nf1 = -sW1 / (127.0f * 127.0f);   // gemm1 dequant (ec3 scale 127)
    const float sWc127 = sW2 / 127.0f;

    // weight A-frags (shared by both tiles): W^T[m=wb+mt*16+L][k=c*64+quad*16+j]
    i32x4 WA[2][4], WC[2][4];
    #pragma unroll
    for (int mt = 0; mt < 2; ++mt) {
        const int m = wb + mt * 16 + L;
        #pragma unroll
        for (int c = 0; c < 4; ++c) {
            WA[mt][c] = *(const i32x4*)&qWap[m * 256 + c * 64 + quad * 16];
            WC[mt][c] = *(const i32x4*)&qWc[m * 256 + c * 64 + quad * 16];
        }
    }

    // persistent zero C-quad
    i32x4 kZero;
    #pragma unroll
    for (int r = 0; r < 4; ++r) kZero[r] = 0;

    // state fp32 (C/D layout): [tile][mt][r]; lane row = row0 + tile*16 + L
    float e5[2][2][4], e3[2][2][4];
    #pragma unroll
    for (int tl = 0; tl < 2; ++tl)
        #pragma unroll
        for (int mt = 0; mt < 2; ++mt) {
            const f32x4 a = *(const f32x4*)&ec5_init[(row0 + tl * 16 + L) * 256 + wb + mt * 16 + quad * 4];
            #pragma unroll
            for (int r = 0; r < 4; ++r) { e5[tl][mt][r] = a[r]; e3[tl][mt][r] = 0.f; }
        }

    // XOR-swizzled stage addresses (within a 4KB buffer; buffer chosen by imm offset)
    int rd[4], wr[2];
    #pragma unroll
    for (int c = 0; c < 4; ++c)
        rd[c] = L * 256 + (((4 * c + quad) ^ L) << 4);
    #pragma unroll
    for (int mt = 0; mt < 2; ++mt)
        wr[mt] = L * 256 + (((wave * 2 + mt) ^ L) << 4) + quad * 4;

    auto gemm = [&](int sb, const i32x4 (&W)[2][4], i32x4 (&acc)[2]) {
        #pragma unroll
        for (int c = 0; c < 4; ++c) {
            const i32x4 bf = *(const i32x4*)&sStage[sb + rd[c]];
            if (c == 0) {
                acc[0] = __builtin_amdgcn_mfma_i32_16x16x64_i8(W[0][c], bf, kZero, 0, 0, 0);
                acc[1] = __builtin_amdgcn_mfma_i32_16x16x64_i8(W[1][c], bf, kZero, 0, 0, 0);
            } else {
                acc[0] = __builtin_amdgcn_mfma_i32_16x16x64_i8(W[0][c], bf, acc[0], 0, 0, 0);
                acc[1] = __builtin_amdgcn_mfma_i32_16x16x64_i8(W[1][c], bf, acc[1], 0, 0, 0);
            }
        }
    };

    // desync co-resident blocks
    if ((blockIdx.x >> 8) & 1) {
        __builtin_amdgcn_s_sleep(15);
        __builtin_amdgcn_s_sleep(15);
    }

    // ===== t = 0 (peeled): ec3=0 -> sigmoid = 0.5; ca1_0 row-independent =====
    {
        #pragma unroll
        for (int mt = 0; mt < 2; ++mt) {
            const int f0 = wb + mt * 16 + quad * 4;
            const f32x4 av = *(const f32x4*)&Atab[f0];
            const f32x4 ev = *(const f32x4*)&Etab[f0];
            unsigned dw = 0;
            #pragma unroll
            for (int r = 0; r < 4; ++r) {
                const float v = fmaxf(fmaf(av[r], 0.5f, ev[r]), 0.0f);
                dw |= ((unsigned)v) << (8 * r);
            }
            *(unsigned*)&sStage[4096 + wr[mt]]  = dw;   // q(ca1_0) tile A
            *(unsigned*)&sStage[12288 + wr[mt]] = dw;   // q(ca1_0) tile B
        }
        __syncthreads();
        const float f2 = ctab[0] * sWc127;
        i32x4 a2A[2], a2B[2];
        gemm(4096, WC, a2A);
        gemm(12288, WC, a2B);
        #pragma unroll
        for (int tl = 0; tl < 2; ++tl) {
            i32x4* a2 = tl ? a2B : a2A;
            const int se = tl ? 8192 : 0;
            #pragma unroll
            for (int mt = 0; mt < 2; ++mt) {
                const f32x4 cv = *(const f32x4*)&cue[(row0 + tl * 16 + L) * 256 + wb + mt * 16 + quad * 4];
                unsigned dw = 0;
                #pragma unroll
                for (int r = 0; r < 4; ++r) {
                    const float n5 = __builtin_amdgcn_fmed3f(
                        fmaf((float)a2[mt][r], f2, e5[tl][mt][r]), 0.0f, 1.0f);
                    const float n3 = __builtin_amdgcn_fmed3f(cv[r], 0.0f, 1.0f);  // ec3_prev=0
                    e5[tl][mt][r] = n5; e3[tl][mt][r] = n3;
                    dw |= ((unsigned)fmaf(n3, 127.0f, 0.5f)) << (8 * r);
                }
                *(unsigned*)&sStage[se + wr[mt]] = dw;   // q(ec3)
            }
        }
        __syncthreads();
    }

    // ===== steady state t = 1..98: 2 phases, 2 barriers, unroll x2 =====
    #pragma unroll 2
    for (int t = 1; t <= 98; ++t) {
        f32x4 avc[2], evc[2];
        #pragma unroll
        for (int mt = 0; mt < 2; ++mt) {
            const int f0 = t * 256 + wb + mt * 16 + quad * 4;
            avc[mt] = *(const f32x4*)&Atab[f0];
            evc[mt] = *(const f32x4*)&Etab[f0];
        }
        const float f2 = ctab[t] * sWc127;

        // Phase A: G1 on both tiles (independent chains, shared weights) + e1 both
        i32x4 accA[2], accB[2];
        gemm(0, WA, accA);
        gemm(8192, WA, accB);
        #pragma unroll
        for (int tl = 0; tl < 2; ++tl) {
            i32x4* acc = tl ? accB : accA;
            const int sc = tl ? 12288 : 4096;
            #pragma unroll
            for (int mt = 0; mt < 2; ++mt) {
                unsigned dw = 0;
                #pragma unroll
                for (int r = 0; r < 4; ++r) {
                    const float s = __builtin_amdgcn_rcpf(1.0f + __expf((float)acc[mt][r] * nf1));
                    const float v = fmaxf(fmaf(avc[mt][r], s, evc[mt][r]), 0.0f);
                    dw |= ((unsigned)v) << (8 * r);
                }
                *(unsigned*)&sStage[sc + wr[mt]] = dw;
            }
        }
        __syncthreads();

        // Phase B: G2 on both tiles + e2 both (state update)
        i32x4 ac2A[2], ac2B[2];
        gemm(4096, WC, ac2A);
        gemm(12288, WC, ac2B);
        #pragma unroll
        for (int tl = 0; tl < 2; ++tl) {
            i32x4* acc2 = tl ? ac2B : ac2A;
            const int se = tl ? 8192 : 0;
            #pragma unroll
            for (int mt = 0; mt < 2; ++mt) {
                unsigned dw = 0;
                #pragma unroll
                for (int r = 0; r < 4; ++r) {
                    const float n5 = __builtin_amdgcn_fmed3f(
                        fmaf((float)acc2[mt][r], f2, e5[tl][mt][r]), 0.0f, 1.0f);
                    const float n3 = n5 * e3[tl][mt][r];   // both in [0,1]: clip redundant
                    e5[tl][mt][r] = n5; e3[tl][mt][r] = n3;
                    dw |= ((unsigned)fmaf(n3, 127.0f, 0.5f)) << (8 * r);
                }
                *(unsigned*)&sStage[se + wr[mt]] = dw;
            }
        }
        __syncthreads();
    }

    // ===== t = 99 (peeled): G1 both + e1 + Waction partial dots =====
    {
        i32x4 accA[2], accB[2];
        gemm(0, WA, accA);
        gemm(8192, WA, accB);
        const float ct = ctab[99];
        #pragma unroll
        for (int tl = 0; tl < 2; ++tl) {
            i32x4* acc = tl ? accB : accA;
            float p0 = 0.f, p1 = 0.f;
            #pragma unroll
            for (int mt = 0; mt < 2; ++mt) {
                const int f0 = wb + mt * 16 + quad * 4;
                const f32x4 av = *(const f32x4*)&Atab[99 * 256 + f0];
                const f32x4 ev = *(const f32x4*)&Etab[99 * 256 + f0];
                const f32x4 w0 = *(const f32x4*)&Wact[f0 * 2];       // feats f0, f0+1
                const f32x4 w1 = *(const f32x4*)&Wact[f0 * 2 + 4];   // feats f0+2, f0+3
                #pragma unroll
                for (int r = 0; r < 4; ++r) {
                    const float s = __builtin_amdgcn_rcpf(1.0f + __expf((float)acc[mt][r] * nf1));
                    const float c = fmaxf(fmaf(av[r], s, ev[r]) - 0.5f, 0.0f) * ct;
                    const float wa = (r & 2) ? ((r & 1) ? w1[2] : w1[0]) : ((r & 1) ? w0[2] : w0[0]);
                    const float wb2 = (r & 2) ? ((r & 1) ? w1[3] : w1[1]) : ((r & 1) ? w0[3] : w0[1]);
                    p0 = fmaf(c, wa, p0);
                    p1 = fmaf(c, wb2, p1);
                }
            }
            p0 += __shfl_xor(p0, 16); p0 += __shfl_xor(p0, 32);
            p1 += __shfl_xor(p1, 16); p1 += __shfl_xor(p1, 32);
            if (quad == 0) {
                sPart[((tl * 16 + L) * 2 + 0) * 8 + wave] = p0;
                sPart[((tl * 16 + L) * 2 + 1) * 8 + wave] = p1;
            }
        }
    }
    __syncthreads();
    if (tid < 64) {
        float s = 0.f;
        #pragma unroll
        for (int g = 0; g < 8; ++g) s += sPart[tid * 8 + g];
        out[row0 * 2 + tid] = s;
    }
}

extern "C" void kernel_launch(void* const* d_in, const int* in_sizes, int n_in,
                              void* d_out, int out_size, void* d_ws, size_t ws_size,
                              hipStream_t stream) {
    const float* cue      = (const float*)d_in[0];
    const float* ec5_init = (const float*)d_in[1];
    const float* Wapical  = (const float*)d_in[2];
    const float* Wbasal   = (const float*)d_in[3];
    const float* Wca1ec5  = (const float*)d_in[4];
    const float* Waction  = (const float*)d_in[5];
    const float* ca1bias  = (const float*)d_in[6];
    float* out = (float*)d_out;

    float* Atab = (float*)d_ws;                  // 25600 f32
    float* Etab = Atab + 25600;                  // 25600 f32
    float* ctab = Etab + 25600;                  // 100 f32
    int*   scaleWS = (int*)(ctab + 100);         // 4 ints
    char*  qWap = (char*)(scaleWS + 4);          // 65536 B
    char*  qWc  = qWap + 65536;                  // 65536 B

    basal2_kernel<<<100, 256, 0, stream>>>(Wbasal, ca1bias, Atab, Etab, ctab, scaleWS);
    wmax_kernel<<<256, 256, 0, stream>>>(Wapical, Wca1ec5, scaleWS);
    wquant_kernel<<<256, 256, 0, stream>>>(Wapical, Wca1ec5, scaleWS, qWap, qWc);
    rnn_kernel<<<1024, 512, 0, stream>>>(cue, ec5_init, qWap, qWc, scaleWS, Waction,
                                         Atab, Etab, ctab, out);
}

// Round 11
// 707.298 us; speedup vs baseline: 1.2518x; 1.2518x over previous
//
#include <hip/hip_runtime.h>

// HPCrnn R11: R10's dual-tile idea with the register budget FIXED (R10 spilled:
// WRITE_SIZE 256KB->516MB). Deltas vs R10: e3 state lives in per-lane LDS
// scratch (-16 VGPR; conflict-free b128 at 16B stride, same-lane RAW only);
// table loads moved after GEMMs and scoped per-mt (-8 peak, shared by tiles).
// Peak live ~122 < 128 cap. Numerics identical to R8 (absmax 9.766e-4).
// 32 rows/block (2 tiles/wave), 8 waves, 2 barriers/step, 2 blocks/CU.

typedef int   i32x4 __attribute__((ext_vector_type(4)));
typedef float f32x4 __attribute__((ext_vector_type(4)));

// ---------- pre 1: basal tables + zero scale slots ----------
__global__ void basal2_kernel(const float* __restrict__ Wbasal,
                              const float* __restrict__ bias,
                              float* __restrict__ Atab, float* __restrict__ Etab,
                              float* __restrict__ ctab, int* __restrict__ scaleWS) {
    const int t = blockIdx.x, n = threadIdx.x;
    __shared__ float ca3s[256], red[256];
    const float x = (float)(t + 1);
    const float c0 = (float)n * (100.0f / 255.0f);
    const float d = (x - c0) * 0.2f;
    ca3s[n] = expf(-0.5f * d * d);
    __syncthreads();
    float bas = 0.f;
    #pragma unroll 8
    for (int k = 0; k < 256; ++k) bas += ca3s[k] * Wbasal[k * 256 + n];
    red[n] = bas;
    __syncthreads();
    for (int s = 128; s > 0; s >>= 1) {
        if (n < s) red[n] = fmaxf(red[n], red[n + s]);
        __syncthreads();
    }
    const float bmax = red[0];
    const float cq = 126.0f / (2.0f * bmax);   // headroom so q(ca1) < 127.5
    Atab[t * 256 + n] = bas * cq;
    Etab[t * 256 + n] = (bas - bias[n]) * cq + 0.5f;   // +0.5 folds rounding
    if (n == 0) ctab[t] = (2.0f * bmax) / 126.0f;
    if (t == 0 && n < 2) scaleWS[n] = 0;
}

// ---------- pre 2: weight absmax ----------
__global__ void wmax_kernel(const float* __restrict__ Wap, const float* __restrict__ Wc,
                            int* __restrict__ scaleWS) {
    const int i = blockIdx.x * 256 + threadIdx.x;
    float m1 = fabsf(Wap[i]);
    float m2 = fabsf(Wc[i]);
    #pragma unroll
    for (int o = 1; o < 64; o <<= 1) {
        m1 = fmaxf(m1, __shfl_xor(m1, o));
        m2 = fmaxf(m2, __shfl_xor(m2, o));
    }
    __shared__ float r1[4], r2[4];
    const int wv = threadIdx.x >> 6, ln = threadIdx.x & 63;
    if (ln == 0) { r1[wv] = m1; r2[wv] = m2; }
    __syncthreads();
    if (threadIdx.x == 0) {
        const float a = fmaxf(fmaxf(r1[0], r1[1]), fmaxf(r1[2], r1[3]));
        const float b = fmaxf(fmaxf(r2[0], r2[1]), fmaxf(r2[2], r2[3]));
        atomicMax(&scaleWS[0], __float_as_int(a));
        atomicMax(&scaleWS[1], __float_as_int(b));
    }
}

// ---------- pre 3: quantize weights to i8, transposed to [m][k] ----------
__global__ void wquant_kernel(const float* __restrict__ Wap, const float* __restrict__ Wc,
                              const int* __restrict__ scaleWS,
                              char* __restrict__ qWap, char* __restrict__ qWc) {
    const int m = blockIdx.x, k = threadIdx.x;
    const float q1 = 127.0f / __int_as_float(scaleWS[0]);
    const float q2 = 127.0f / __int_as_float(scaleWS[1]);
    qWap[m * 256 + k] = (char)(int)rintf(Wap[k * 256 + m] * q1);
    qWc[m * 256 + k]  = (char)(int)rintf(Wc[k * 256 + m] * q2);
}

// ---------- main ----------
__global__ __launch_bounds__(512, 4) void rnn_kernel(
    const float* __restrict__ cue, const float* __restrict__ ec5_init,
    const char* __restrict__ qWap, const char* __restrict__ qWc,
    const int* __restrict__ scaleWS, const float* __restrict__ Wact,
    const float* __restrict__ Atab, const float* __restrict__ Etab,
    const float* __restrict__ ctab, float* __restrict__ out)
{
    // LDS map: EA@0 CA@4096 EB@8192 CB@12288 | e3 scratch @16384 (32KB) | sPart @49152
    __shared__ __align__(16) char sStage[51200];
    float* sPart = (float*)&sStage[49152];

    const int tid  = threadIdx.x;
    const int wave = tid >> 6;
    const int lane = tid & 63;
    const int quad = lane >> 4;
    const int L    = lane & 15;
    const int wb   = wave * 32;
    const int row0 = blockIdx.x * 32;   // tile A rows row0+L, tile B rows row0+16+L

    const float sW1 = __int_as_float(scaleWS[0]);
    const float sW2 = __int_as_float(scaleWS[1]);
    const float nf1 = -sW1 / (127.0f * 127.0f);   // gemm1 dequant (ec3 scale 127)
    const float sWc127 = sW2 / 127.0f;

    // weight A-frags (shared by both tiles): W^T[m=wb+mt*16+L][k=c*64+quad*16+j]
    i32x4 WA[2][4], WC[2][4];
    #pragma unroll
    for (int mt = 0; mt < 2; ++mt) {
        const int m = wb + mt * 16 + L;
        #pragma unroll
        for (int c = 0; c < 4; ++c) {
            WA[mt][c] = *(const i32x4*)&qWap[m * 256 + c * 64 + quad * 16];
            WC[mt][c] = *(const i32x4*)&qWc[m * 256 + c * 64 + quad * 16];
        }
    }

    // persistent zero C-quad
    i32x4 kZero;
    #pragma unroll
    for (int r = 0; r < 4; ++r) kZero[r] = 0;

    // e5 state fp32 in regs (16): [tile][mt], lane row = row0 + tile*16 + L
    f32x4 e5v[2][2];
    #pragma unroll
    for (int tl = 0; tl < 2; ++tl)
        #pragma unroll
        for (int mt = 0; mt < 2; ++mt)
            e5v[tl][mt] = *(const f32x4*)&ec5_init[(row0 + tl * 16 + L) * 256 + wb + mt * 16 + quad * 4];

    // e3 state in per-lane LDS scratch: group g = tl*2+mt holds f32x4
    // addr = 16384 + wave*4096 + g*1024 + lane*16 (16B stride -> conflict-free b128)
    const int e3ad = 16384 + wave * 4096 + lane * 16;

    // XOR-swizzled stage addresses (within each 4KB buffer)
    int rd[4], wr[2];
    #pragma unroll
    for (int c = 0; c < 4; ++c)
        rd[c] = L * 256 + (((4 * c + quad) ^ L) << 4);
    #pragma unroll
    for (int mt = 0; mt < 2; ++mt)
        wr[mt] = L * 256 + (((wave * 2 + mt) ^ L) << 4) + quad * 4;

    auto gemm = [&](int sb, const i32x4 (&W)[2][4], i32x4 (&acc)[2]) {
        #pragma unroll
        for (int c = 0; c < 4; ++c) {
            const i32x4 bf = *(const i32x4*)&sStage[sb + rd[c]];
            if (c == 0) {
                acc[0] = __builtin_amdgcn_mfma_i32_16x16x64_i8(W[0][c], bf, kZero, 0, 0, 0);
                acc[1] = __builtin_amdgcn_mfma_i32_16x16x64_i8(W[1][c], bf, kZero, 0, 0, 0);
            } else {
                acc[0] = __builtin_amdgcn_mfma_i32_16x16x64_i8(W[0][c], bf, acc[0], 0, 0, 0);
                acc[1] = __builtin_amdgcn_mfma_i32_16x16x64_i8(W[1][c], bf, acc[1], 0, 0, 0);
            }
        }
    };

    // desync co-resident blocks
    if ((blockIdx.x >> 8) & 1) {
        __builtin_amdgcn_s_sleep(15);
        __builtin_amdgcn_s_sleep(15);
    }

    // ===== t = 0 (peeled): ec3=0 -> sigmoid = 0.5; ca1_0 row-independent =====
    {
        #pragma unroll
        for (int mt = 0; mt < 2; ++mt) {
            const int f0 = wb + mt * 16 + quad * 4;
            const f32x4 av = *(const f32x4*)&Atab[f0];
            const f32x4 ev = *(const f32x4*)&Etab[f0];
            unsigned dw = 0;
            #pragma unroll
            for (int r = 0; r < 4; ++r) {
                const float v = fmaxf(fmaf(av[r], 0.5f, ev[r]), 0.0f);
                dw |= ((unsigned)v) << (8 * r);
            }
            *(unsigned*)&sStage[4096 + wr[mt]]  = dw;   // q(ca1_0) tile A
            *(unsigned*)&sStage[12288 + wr[mt]] = dw;   // q(ca1_0) tile B
        }
        __syncthreads();
        const float f2 = ctab[0] * sWc127;
        i32x4 a2A[2], a2B[2];
        gemm(4096, WC, a2A);
        gemm(12288, WC, a2B);
        #pragma unroll
        for (int tl = 0; tl < 2; ++tl) {
            i32x4* a2 = tl ? a2B : a2A;
            const int se = tl ? 8192 : 0;
            #pragma unroll
            for (int mt = 0; mt < 2; ++mt) {
                const f32x4 cv = *(const f32x4*)&cue[(row0 + tl * 16 + L) * 256 + wb + mt * 16 + quad * 4];
                f32x4 n3;
                unsigned dw = 0;
                #pragma unroll
                for (int r = 0; r < 4; ++r) {
                    const float n5 = __builtin_amdgcn_fmed3f(
                        fmaf((float)a2[mt][r], f2, e5v[tl][mt][r]), 0.0f, 1.0f);
                    n3[r] = __builtin_amdgcn_fmed3f(cv[r], 0.0f, 1.0f);  // ec3_prev=0
                    e5v[tl][mt][r] = n5;
                    dw |= ((unsigned)fmaf(n3[r], 127.0f, 0.5f)) << (8 * r);
                }
                *(f32x4*)&sStage[e3ad + (tl * 2 + mt) * 1024] = n3;   // e3 state
                *(unsigned*)&sStage[se + wr[mt]] = dw;                // q(ec3)
            }
        }
        __syncthreads();
    }

    // ===== steady state t = 1..98: 2 phases, 2 barriers, unroll x2 =====
    #pragma unroll 2
    for (int t = 1; t <= 98; ++t) {
        // Phase A: G1 on both tiles, then e1 both (tables loaded per-mt, shared)
        i32x4 accA[2], accB[2];
        gemm(0, WA, accA);
        gemm(8192, WA, accB);
        #pragma unroll
        for (int mt = 0; mt < 2; ++mt) {
            const int f0 = t * 256 + wb + mt * 16 + quad * 4;
            const f32x4 av = *(const f32x4*)&Atab[f0];
            const f32x4 ev = *(const f32x4*)&Etab[f0];
            unsigned dwA = 0, dwB = 0;
            #pragma unroll
            for (int r = 0; r < 4; ++r) {
                const float sA = __builtin_amdgcn_rcpf(1.0f + __expf((float)accA[mt][r] * nf1));
                const float sB = __builtin_amdgcn_rcpf(1.0f + __expf((float)accB[mt][r] * nf1));
                dwA |= ((unsigned)fmaxf(fmaf(av[r], sA, ev[r]), 0.0f)) << (8 * r);
                dwB |= ((unsigned)fmaxf(fmaf(av[r], sB, ev[r]), 0.0f)) << (8 * r);
            }
            *(unsigned*)&sStage[4096 + wr[mt]]  = dwA;
            *(unsigned*)&sStage[12288 + wr[mt]] = dwB;
        }
        __syncthreads();

        // Phase B: G2 on both tiles, then e2 both (e3 via LDS scratch)
        const float f2 = ctab[t] * sWc127;
        i32x4 ac2A[2], ac2B[2];
        gemm(4096, WC, ac2A);
        gemm(12288, WC, ac2B);
        #pragma unroll
        for (int tl = 0; tl < 2; ++tl) {
            i32x4* acc2 = tl ? ac2B : ac2A;
            const int se = tl ? 8192 : 0;
            #pragma unroll
            for (int mt = 0; mt < 2; ++mt) {
                const f32x4 e3g = *(const f32x4*)&sStage[e3ad + (tl * 2 + mt) * 1024];
                f32x4 n3;
                unsigned dw = 0;
                #pragma unroll
                for (int r = 0; r < 4; ++r) {
                    const float n5 = __builtin_amdgcn_fmed3f(
                        fmaf((float)acc2[mt][r], f2, e5v[tl][mt][r]), 0.0f, 1.0f);
                    n3[r] = n5 * e3g[r];   // both in [0,1]: clip redundant
                    e5v[tl][mt][r] = n5;
                    dw |= ((unsigned)fmaf(n3[r], 127.0f, 0.5f)) << (8 * r);
                }
                *(f32x4*)&sStage[e3ad + (tl * 2 + mt) * 1024] = n3;
                *(unsigned*)&sStage[se + wr[mt]] = dw;
            }
        }
        __syncthreads();
    }

    // ===== t = 99 (peeled): G1 both + e1 + Waction partial dots =====
    {
        i32x4 accA[2], accB[2];
        gemm(0, WA, accA);
        gemm(8192, WA, accB);
        const float ct = ctab[99];
        #pragma unroll
        for (int tl = 0; tl < 2; ++tl) {
            i32x4* acc = tl ? accB : accA;
            float p0 = 0.f, p1 = 0.f;
            #pragma unroll
            for (int mt = 0; mt < 2; ++mt) {
                const int f0 = wb + mt * 16 + quad * 4;
                const f32x4 av = *(const f32x4*)&Atab[99 * 256 + f0];
                const f32x4 ev = *(const f32x4*)&Etab[99 * 256 + f0];
                const f32x4 w0 = *(const f32x4*)&Wact[f0 * 2];       // feats f0, f0+1
                const f32x4 w1 = *(const f32x4*)&Wact[f0 * 2 + 4];   // feats f0+2, f0+3
                #pragma unroll
                for (int r = 0; r < 4; ++r) {
                    const float s = __builtin_amdgcn_rcpf(1.0f + __expf((float)acc[mt][r] * nf1));
                    const float c = fmaxf(fmaf(av[r], s, ev[r]) - 0.5f, 0.0f) * ct;
                    const float wa = (r & 2) ? ((r & 1) ? w1[2] : w1[0]) : ((r & 1) ? w0[2] : w0[0]);
                    const float wb2 = (r & 2) ? ((r & 1) ? w1[3] : w1[1]) : ((r & 1) ? w0[3] : w0[1]);
                    p0 = fmaf(c, wa, p0);
                    p1 = fmaf(c, wb2, p1);
                }
            }
            p0 += __shfl_xor(p0, 16); p0 += __shfl_xor(p0, 32);
            p1 += __shfl_xor(p1, 16); p1 += __shfl_xor(p1, 32);
            if (quad == 0) {
                sPart[((tl * 16 + L) * 2 + 0) * 8 + wave] = p0;
                sPart[((tl * 16 + L) * 2 + 1) * 8 + wave] = p1;
            }
        }
    }
    __syncthreads();
    if (tid < 64) {
        float s = 0.f;
        #pragma unroll
        for (int g = 0; g < 8; ++g) s += sPart[tid * 8 + g];
        out[row0 * 2 + tid] = s;
    }
}

extern "C" void kernel_launch(void* const* d_in, const int* in_sizes, int n_in,
                              void* d_out, int out_size, void* d_ws, size_t ws_size,
                              hipStream_t stream) {
    const float* cue      = (const float*)d_in[0];
    const float* ec5_init = (const float*)d_in[1];
    const float* Wapical  = (const float*)d_in[2];
    const float* Wbasal   = (const float*)d_in[3];
    const float* Wca1ec5  = (const float*)d_in[4];
    const float* Waction  = (const float*)d_in[5];
    const float* ca1bias  = (const float*)d_in[6];
    float* out = (float*)d_out;

    float* Atab = (float*)d_ws;                  // 25600 f32
    float* Etab = Atab + 25600;                  // 25600 f32
    float* ctab = Etab + 25600;                  // 100 f32
    int*   scaleWS = (int*)(ctab + 100);         // 4 ints
    char*  qWap = (char*)(scaleWS + 4);          // 65536 B
    char*  qWc  = qWap + 65536;                  // 65536 B

    basal2_kernel<<<100, 256, 0, stream>>>(Wbasal, ca1bias, Atab, Etab, ctab, scaleWS);
    wmax_kernel<<<256, 256, 0, stream>>>(Wapical, Wca1ec5, scaleWS);
    wquant_kernel<<<256, 256, 0, stream>>>(Wapical, Wca1ec5, scaleWS, qWap, qWc);
    rnn_kernel<<<1024, 512, 0, stream>>>(cue, ec5_init, qWap, qWc, scaleWS, Waction,
                                         Atab, Etab, ctab, out);
}

// Round 12
// 614.005 us; speedup vs baseline: 1.4419x; 1.1519x over previous
//
#include <hip/hip_runtime.h>

// HPCrnn R12 = R8 verbatim (measured best: 618 us). 11 rounds of evidence:
// every structural alternative (wave-private LDS weights, phase stagger,
// VALU diets x2, dual-tile x2) measured worse. This config: 16-row blocks,
// 8 waves, i8 16x16x64 MFMA with both weight matrices register-resident
// (64 VGPR), 2 blocks/CU via __launch_bounds__(512,4), 2 barriers/step,
// kZero acc-init, co-resident-block desync, t-loop unroll x2.

typedef int   i32x4 __attribute__((ext_vector_type(4)));
typedef float f32x4 __attribute__((ext_vector_type(4)));

// ---------- pre 1: basal tables + zero scale slots ----------
__global__ void basal2_kernel(const float* __restrict__ Wbasal,
                              const float* __restrict__ bias,
                              float* __restrict__ Atab, float* __restrict__ Etab,
                              float* __restrict__ ctab, int* __restrict__ scaleWS) {
    const int t = blockIdx.x, n = threadIdx.x;
    __shared__ float ca3s[256], red[256];
    const float x = (float)(t + 1);
    const float c0 = (float)n * (100.0f / 255.0f);
    const float d = (x - c0) * 0.2f;
    ca3s[n] = expf(-0.5f * d * d);
    __syncthreads();
    float bas = 0.f;
    #pragma unroll 8
    for (int k = 0; k < 256; ++k) bas += ca3s[k] * Wbasal[k * 256 + n];
    red[n] = bas;
    __syncthreads();
    for (int s = 128; s > 0; s >>= 1) {
        if (n < s) red[n] = fmaxf(red[n], red[n + s]);
        __syncthreads();
    }
    const float bmax = red[0];
    const float cq = 126.0f / (2.0f * bmax);   // headroom so q(ca1) < 127.5
    Atab[t * 256 + n] = bas * cq;
    Etab[t * 256 + n] = (bas - bias[n]) * cq + 0.5f;   // +0.5 folds rounding
    if (n == 0) ctab[t] = (2.0f * bmax) / 126.0f;
    if (t == 0 && n < 2) scaleWS[n] = 0;
}

// ---------- pre 2: weight absmax ----------
__global__ void wmax_kernel(const float* __restrict__ Wap, const float* __restrict__ Wc,
                            int* __restrict__ scaleWS) {
    const int i = blockIdx.x * 256 + threadIdx.x;
    float m1 = fabsf(Wap[i]);
    float m2 = fabsf(Wc[i]);
    #pragma unroll
    for (int o = 1; o < 64; o <<= 1) {
        m1 = fmaxf(m1, __shfl_xor(m1, o));
        m2 = fmaxf(m2, __shfl_xor(m2, o));
    }
    __shared__ float r1[4], r2[4];
    const int wv = threadIdx.x >> 6, ln = threadIdx.x & 63;
    if (ln == 0) { r1[wv] = m1; r2[wv] = m2; }
    __syncthreads();
    if (threadIdx.x == 0) {
        const float a = fmaxf(fmaxf(r1[0], r1[1]), fmaxf(r1[2], r1[3]));
        const float b = fmaxf(fmaxf(r2[0], r2[1]), fmaxf(r2[2], r2[3]));
        atomicMax(&scaleWS[0], __float_as_int(a));
        atomicMax(&scaleWS[1], __float_as_int(b));
    }
}

// ---------- pre 3: quantize weights to i8, transposed to [m][k] ----------
__global__ void wquant_kernel(const float* __restrict__ Wap, const float* __restrict__ Wc,
                              const int* __restrict__ scaleWS,
                              char* __restrict__ qWap, char* __restrict__ qWc) {
    const int m = blockIdx.x, k = threadIdx.x;
    const float q1 = 127.0f / __int_as_float(scaleWS[0]);
    const float q2 = 127.0f / __int_as_float(scaleWS[1]);
    qWap[m * 256 + k] = (char)(int)rintf(Wap[k * 256 + m] * q1);
    qWc[m * 256 + k]  = (char)(int)rintf(Wc[k * 256 + m] * q2);
}

// ---------- main: 16 rows/block, 8 waves, 2 barriers/step, 2 blocks/CU ----------
__global__ __launch_bounds__(512, 4) void rnn_kernel(
    const float* __restrict__ cue, const float* __restrict__ ec5_init,
    const char* __restrict__ qWap, const char* __restrict__ qWc,
    const int* __restrict__ scaleWS, const float* __restrict__ Wact,
    const float* __restrict__ Atab, const float* __restrict__ Etab,
    const float* __restrict__ ctab, float* __restrict__ out)
{
    __shared__ __align__(16) char sStage[8192 + 1024];  // sE@0, sC@4096, sPart@8192
    float* sPart = (float*)&sStage[8192];

    const int tid  = threadIdx.x;
    const int wave = tid >> 6;
    const int lane = tid & 63;
    const int quad = lane >> 4;
    const int L    = lane & 15;
    const int wb   = wave * 32;
    const int row0 = blockIdx.x * 16;

    const float sW1 = __int_as_float(scaleWS[0]);
    const float sW2 = __int_as_float(scaleWS[1]);
    const float nf1 = -sW1 / (127.0f * 127.0f);   // gemm1 dequant (ec3 scale 127)
    const float sWc127 = sW2 / 127.0f;

    // weight A-frags: lane (quad,L) holds W^T[m=wb+mt*16+L][k=c*64+quad*16+j]
    i32x4 WA[2][4], WC[2][4];
    #pragma unroll
    for (int mt = 0; mt < 2; ++mt) {
        const int m = wb + mt * 16 + L;
        #pragma unroll
        for (int c = 0; c < 4; ++c) {
            WA[mt][c] = *(const i32x4*)&qWap[m * 256 + c * 64 + quad * 16];
            WC[mt][c] = *(const i32x4*)&qWc[m * 256 + c * 64 + quad * 16];
        }
    }

    // persistent zero C-quad: first MFMA reads it instead of zero-initing AGPRs
    i32x4 kZero;
    #pragma unroll
    for (int r = 0; r < 4; ++r) kZero[r] = 0;

    // state fp32 (C/D layout): lane (quad,L) holds row row0+L, feats wb+mt*16+quad*4+r
    float e5[2][4], e3[2][4];
    #pragma unroll
    for (int mt = 0; mt < 2; ++mt) {
        const f32x4 a = *(const f32x4*)&ec5_init[(row0 + L) * 256 + wb + mt * 16 + quad * 4];
        #pragma unroll
        for (int r = 0; r < 4; ++r) { e5[mt][r] = a[r]; e3[mt][r] = 0.f; }
    }

    // XOR-swizzled stage addresses (16B blocks xor'd with row L)
    int rd[4], wr[2];
    #pragma unroll
    for (int c = 0; c < 4; ++c)
        rd[c] = L * 256 + (((4 * c + quad) ^ L) << 4);
    #pragma unroll
    for (int mt = 0; mt < 2; ++mt)
        wr[mt] = L * 256 + (((wave * 2 + mt) ^ L) << 4) + quad * 4;

    auto gemm = [&](int sb, const i32x4 (&W)[2][4], i32x4 (&acc)[2]) {
        #pragma unroll
        for (int c = 0; c < 4; ++c) {
            const i32x4 bf = *(const i32x4*)&sStage[sb + rd[c]];
            if (c == 0) {
                acc[0] = __builtin_amdgcn_mfma_i32_16x16x64_i8(W[0][c], bf, kZero, 0, 0, 0);
                acc[1] = __builtin_amdgcn_mfma_i32_16x16x64_i8(W[1][c], bf, kZero, 0, 0, 0);
            } else {
                acc[0] = __builtin_amdgcn_mfma_i32_16x16x64_i8(W[0][c], bf, acc[0], 0, 0, 0);
                acc[1] = __builtin_amdgcn_mfma_i32_16x16x64_i8(W[1][c], bf, acc[1], 0, 0, 0);
            }
        }
    };

    // desync: co-resident blocks (ids ~256 apart) anti-phase their barriers
    if ((blockIdx.x >> 8) & 1) {
        __builtin_amdgcn_s_sleep(15);
        __builtin_amdgcn_s_sleep(15);
    }

    // ===== t = 0 (peeled): ec3=0 -> sigmoid = 0.5 exactly; ca1 row-independent =====
    {
        #pragma unroll
        for (int mt = 0; mt < 2; ++mt) {
            const int f0 = wb + mt * 16 + quad * 4;
            const f32x4 av = *(const f32x4*)&Atab[f0];
            const f32x4 ev = *(const f32x4*)&Etab[f0];
            unsigned dw = 0;
            #pragma unroll
            for (int r = 0; r < 4; ++r) {
                const float v = fmaxf(fmaf(av[r], 0.5f, ev[r]), 0.0f);
                dw |= ((unsigned)v) << (8 * r);
            }
            *(unsigned*)&sStage[4096 + wr[mt]] = dw;   // q(ca1_0)
        }
        __syncthreads();
        const float f2 = ctab[0] * sWc127;
        i32x4 acc2[2];
        gemm(4096, WC, acc2);
        #pragma unroll
        for (int mt = 0; mt < 2; ++mt) {
            const f32x4 cv = *(const f32x4*)&cue[(row0 + L) * 256 + wb + mt * 16 + quad * 4];
            unsigned dw = 0;
            #pragma unroll
            for (int r = 0; r < 4; ++r) {
                const float n5 = __builtin_amdgcn_fmed3f(
                    fmaf((float)acc2[mt][r], f2, e5[mt][r]), 0.0f, 1.0f);
                const float n3 = __builtin_amdgcn_fmed3f(cv[r], 0.0f, 1.0f);  // ec3_prev=0
                e5[mt][r] = n5; e3[mt][r] = n3;
                dw |= ((unsigned)fmaf(n3, 127.0f, 0.5f)) << (8 * r);
            }
            *(unsigned*)&sStage[wr[mt]] = dw;   // q(ec3)
        }
        __syncthreads();
    }

    // ===== steady state t = 1..98: 2 phases, 2 barriers, unroll x2 =====
    #pragma unroll 2
    for (int t = 1; t <= 98; ++t) {
        f32x4 avc[2], evc[2];
        #pragma unroll
        for (int mt = 0; mt < 2; ++mt) {
            const int f0 = t * 256 + wb + mt * 16 + quad * 4;
            avc[mt] = *(const f32x4*)&Atab[f0];
            evc[mt] = *(const f32x4*)&Etab[f0];
        }
        const float f2 = ctab[t] * sWc127;

        // Phase A: G1 (sE -> acc) + e1 (-> sC)
        i32x4 acc[2];
        gemm(0, WA, acc);
        #pragma unroll
        for (int mt = 0; mt < 2; ++mt) {
            unsigned dw = 0;
            #pragma unroll
            for (int r = 0; r < 4; ++r) {
                const float s = __builtin_amdgcn_rcpf(1.0f + __expf((float)acc[mt][r] * nf1));
                const float v = fmaxf(fmaf(avc[mt][r], s, evc[mt][r]), 0.0f);
                dw |= ((unsigned)v) << (8 * r);
            }
            *(unsigned*)&sStage[4096 + wr[mt]] = dw;
        }
        __syncthreads();

        // Phase B: G2 (sC -> acc2) + e2 (-> sE, state update)
        i32x4 acc2[2];
        gemm(4096, WC, acc2);
        #pragma unroll
        for (int mt = 0; mt < 2; ++mt) {
            unsigned dw = 0;
            #pragma unroll
            for (int r = 0; r < 4; ++r) {
                const float n5 = __builtin_amdgcn_fmed3f(
                    fmaf((float)acc2[mt][r], f2, e5[mt][r]), 0.0f, 1.0f);
                const float n3 = n5 * e3[mt][r];   // both in [0,1]: clip redundant
                e5[mt][r] = n5; e3[mt][r] = n3;
                dw |= ((unsigned)fmaf(n3, 127.0f, 0.5f)) << (8 * r);
            }
            *(unsigned*)&sStage[wr[mt]] = dw;
        }
        __syncthreads();
    }

    // ===== t = 99 (peeled): G1 + e1 + Waction partial dot =====
    {
        i32x4 acc[2];
        gemm(0, WA, acc);
        const float ct = ctab[99];
        float p0 = 0.f, p1 = 0.f;
        #pragma unroll
        for (int mt = 0; mt < 2; ++mt) {
            const int f0 = wb + mt * 16 + quad * 4;
            const f32x4 av = *(const f32x4*)&Atab[99 * 256 + f0];
            const f32x4 ev = *(const f32x4*)&Etab[99 * 256 + f0];
            const f32x4 w0 = *(const f32x4*)&Wact[f0 * 2];       // feats f0, f0+1
            const f32x4 w1 = *(const f32x4*)&Wact[f0 * 2 + 4];   // feats f0+2, f0+3
            #pragma unroll
            for (int r = 0; r < 4; ++r) {
                const float s = __builtin_amdgcn_rcpf(1.0f + __expf((float)acc[mt][r] * nf1));
                const float c = fmaxf(fmaf(av[r], s, ev[r]) - 0.5f, 0.0f) * ct;
                const float wa = (r & 2) ? ((r & 1) ? w1[2] : w1[0]) : ((r & 1) ? w0[2] : w0[0]);
                const float wb2 = (r & 2) ? ((r & 1) ? w1[3] : w1[1]) : ((r & 1) ? w0[3] : w0[1]);
                p0 = fmaf(c, wa, p0);
                p1 = fmaf(c, wb2, p1);
            }
        }
        p0 += __shfl_xor(p0, 16); p0 += __shfl_xor(p0, 32);
        p1 += __shfl_xor(p1, 16); p1 += __shfl_xor(p1, 32);
        if (quad == 0) {
            sPart[(L * 2 + 0) * 8 + wave] = p0;
            sPart[(L * 2 + 1) * 8 + wave] = p1;
        }
    }
    __syncthreads();
    if (tid < 32) {
        float s = 0.f;
        #pragma unroll
        for (int g = 0; g < 8; ++g) s += sPart[tid * 8 + g];
        out[row0 * 2 + tid] = s;
    }
}

extern "C" void kernel_launch(void* const* d_in, const int* in_sizes, int n_in,
                              void* d_out, int out_size, void* d_ws, size_t ws_size,
                              hipStream_t stream) {
    const float* cue      = (const float*)d_in[0];
    const float* ec5_init = (const float*)d_in[1];
    const float* Wapical  = (const float*)d_in[2];
    const float* Wbasal   = (const float*)d_in[3];
    const float* Wca1ec5  = (const float*)d_in[4];
    const float* Waction  = (const float*)d_in[5];
    const float* ca1bias  = (const float*)d_in[6];
    float* out = (float*)d_out;

    float* Atab = (float*)d_ws;                  // 25600 f32
    float* Etab = Atab + 25600;                  // 25600 f32
    float* ctab = Etab + 25600;                  // 100 f32
    int*   scaleWS = (int*)(ctab + 100);         // 4 ints
    char*  qWap = (char*)(scaleWS + 4);          // 65536 B
    char*  qWc  = qWap + 65536;                  // 65536 B

    basal2_kernel<<<100, 256, 0, stream>>>(Wbasal, ca1bias, Atab, Etab, ctab, scaleWS);
    wmax_kernel<<<256, 256, 0, stream>>>(Wapical, Wca1ec5, scaleWS);
    wquant_kernel<<<256, 256, 0, stream>>>(Wapical, Wca1ec5, scaleWS, qWap, qWc);
    rnn_kernel<<<2048, 512, 0, stream>>>(cue, ec5_init, qWap, qWc, scaleWS, Waction,
                                         Atab, Etab, ctab, out);
}

// Round 13
// 600.680 us; speedup vs baseline: 1.4739x; 1.0222x over previous
//
#include <hip/hip_runtime.h>

// HPCrnn R13: R12 (=R8, measured best 614us, reproduced) + ONE isolated delta:
// v_cvt_pk_u8_f32 for the quant byte-pack (cvt_u32+lshl+or -> 1 op/elem).
// Rationale: R7/R9 showed transcendentals co-issue (replacing them regressed);
// the pack is the largest pure main-VALU item (~3 ops/elem x 16 elems/step).
// R9 proved cvt_pk_u8 is numerically exact here (absmax unchanged); its
// regression came from the bundled f32x4 epilogue restructure, not the pack.
// Everything else byte-identical to R12.

typedef int   i32x4 __attribute__((ext_vector_type(4)));
typedef float f32x4 __attribute__((ext_vector_type(4)));

#if __has_builtin(__builtin_amdgcn_cvt_pk_u8_f32)
#define PKU8(v, r, dw) __builtin_amdgcn_cvt_pk_u8_f32((v), (r), (dw))
#else
#define PKU8(v, r, dw) ((dw) | (((unsigned)(v)) << (8 * (r))))
#endif

// ---------- pre 1: basal tables + zero scale slots ----------
__global__ void basal2_kernel(const float* __restrict__ Wbasal,
                              const float* __restrict__ bias,
                              float* __restrict__ Atab, float* __restrict__ Etab,
                              float* __restrict__ ctab, int* __restrict__ scaleWS) {
    const int t = blockIdx.x, n = threadIdx.x;
    __shared__ float ca3s[256], red[256];
    const float x = (float)(t + 1);
    const float c0 = (float)n * (100.0f / 255.0f);
    const float d = (x - c0) * 0.2f;
    ca3s[n] = expf(-0.5f * d * d);
    __syncthreads();
    float bas = 0.f;
    #pragma unroll 8
    for (int k = 0; k < 256; ++k) bas += ca3s[k] * Wbasal[k * 256 + n];
    red[n] = bas;
    __syncthreads();
    for (int s = 128; s > 0; s >>= 1) {
        if (n < s) red[n] = fmaxf(red[n], red[n + s]);
        __syncthreads();
    }
    const float bmax = red[0];
    const float cq = 126.0f / (2.0f * bmax);   // headroom so q(ca1) < 127.5
    Atab[t * 256 + n] = bas * cq;
    Etab[t * 256 + n] = (bas - bias[n]) * cq + 0.5f;   // +0.5 folds rounding
    if (n == 0) ctab[t] = (2.0f * bmax) / 126.0f;
    if (t == 0 && n < 2) scaleWS[n] = 0;
}

// ---------- pre 2: weight absmax ----------
__global__ void wmax_kernel(const float* __restrict__ Wap, const float* __restrict__ Wc,
                            int* __restrict__ scaleWS) {
    const int i = blockIdx.x * 256 + threadIdx.x;
    float m1 = fabsf(Wap[i]);
    float m2 = fabsf(Wc[i]);
    #pragma unroll
    for (int o = 1; o < 64; o <<= 1) {
        m1 = fmaxf(m1, __shfl_xor(m1, o));
        m2 = fmaxf(m2, __shfl_xor(m2, o));
    }
    __shared__ float r1[4], r2[4];
    const int wv = threadIdx.x >> 6, ln = threadIdx.x & 63;
    if (ln == 0) { r1[wv] = m1; r2[wv] = m2; }
    __syncthreads();
    if (threadIdx.x == 0) {
        const float a = fmaxf(fmaxf(r1[0], r1[1]), fmaxf(r1[2], r1[3]));
        const float b = fmaxf(fmaxf(r2[0], r2[1]), fmaxf(r2[2], r2[3]));
        atomicMax(&scaleWS[0], __float_as_int(a));
        atomicMax(&scaleWS[1], __float_as_int(b));
    }
}

// ---------- pre 3: quantize weights to i8, transposed to [m][k] ----------
__global__ void wquant_kernel(const float* __restrict__ Wap, const float* __restrict__ Wc,
                              const int* __restrict__ scaleWS,
                              char* __restrict__ qWap, char* __restrict__ qWc) {
    const int m = blockIdx.x, k = threadIdx.x;
    const float q1 = 127.0f / __int_as_float(scaleWS[0]);
    const float q2 = 127.0f / __int_as_float(scaleWS[1]);
    qWap[m * 256 + k] = (char)(int)rintf(Wap[k * 256 + m] * q1);
    qWc[m * 256 + k]  = (char)(int)rintf(Wc[k * 256 + m] * q2);
}

// ---------- main: 16 rows/block, 8 waves, 2 barriers/step, 2 blocks/CU ----------
__global__ __launch_bounds__(512, 4) void rnn_kernel(
    const float* __restrict__ cue, const float* __restrict__ ec5_init,
    const char* __restrict__ qWap, const char* __restrict__ qWc,
    const int* __restrict__ scaleWS, const float* __restrict__ Wact,
    const float* __restrict__ Atab, const float* __restrict__ Etab,
    const float* __restrict__ ctab, float* __restrict__ out)
{
    __shared__ __align__(16) char sStage[8192 + 1024];  // sE@0, sC@4096, sPart@8192
    float* sPart = (float*)&sStage[8192];

    const int tid  = threadIdx.x;
    const int wave = tid >> 6;
    const int lane = tid & 63;
    const int quad = lane >> 4;
    const int L    = lane & 15;
    const int wb   = wave * 32;
    const int row0 = blockIdx.x * 16;

    const float sW1 = __int_as_float(scaleWS[0]);
    const float sW2 = __int_as_float(scaleWS[1]);
    const float nf1 = -sW1 / (127.0f * 127.0f);   // gemm1 dequant (ec3 scale 127)
    const float sWc127 = sW2 / 127.0f;

    // weight A-frags: lane (quad,L) holds W^T[m=wb+mt*16+L][k=c*64+quad*16+j]
    i32x4 WA[2][4], WC[2][4];
    #pragma unroll
    for (int mt = 0; mt < 2; ++mt) {
        const int m = wb + mt * 16 + L;
        #pragma unroll
        for (int c = 0; c < 4; ++c) {
            WA[mt][c] = *(const i32x4*)&qWap[m * 256 + c * 64 + quad * 16];
            WC[mt][c] = *(const i32x4*)&qWc[m * 256 + c * 64 + quad * 16];
        }
    }

    // persistent zero C-quad: first MFMA reads it instead of zero-initing AGPRs
    i32x4 kZero;
    #pragma unroll
    for (int r = 0; r < 4; ++r) kZero[r] = 0;

    // state fp32 (C/D layout): lane (quad,L) holds row row0+L, feats wb+mt*16+quad*4+r
    float e5[2][4], e3[2][4];
    #pragma unroll
    for (int mt = 0; mt < 2; ++mt) {
        const f32x4 a = *(const f32x4*)&ec5_init[(row0 + L) * 256 + wb + mt * 16 + quad * 4];
        #pragma unroll
        for (int r = 0; r < 4; ++r) { e5[mt][r] = a[r]; e3[mt][r] = 0.f; }
    }

    // XOR-swizzled stage addresses (16B blocks xor'd with row L)
    int rd[4], wr[2];
    #pragma unroll
    for (int c = 0; c < 4; ++c)
        rd[c] = L * 256 + (((4 * c + quad) ^ L) << 4);
    #pragma unroll
    for (int mt = 0; mt < 2; ++mt)
        wr[mt] = L * 256 + (((wave * 2 + mt) ^ L) << 4) + quad * 4;

    auto gemm = [&](int sb, const i32x4 (&W)[2][4], i32x4 (&acc)[2]) {
        #pragma unroll
        for (int c = 0; c < 4; ++c) {
            const i32x4 bf = *(const i32x4*)&sStage[sb + rd[c]];
            if (c == 0) {
                acc[0] = __builtin_amdgcn_mfma_i32_16x16x64_i8(W[0][c], bf, kZero, 0, 0, 0);
                acc[1] = __builtin_amdgcn_mfma_i32_16x16x64_i8(W[1][c], bf, kZero, 0, 0, 0);
            } else {
                acc[0] = __builtin_amdgcn_mfma_i32_16x16x64_i8(W[0][c], bf, acc[0], 0, 0, 0);
                acc[1] = __builtin_amdgcn_mfma_i32_16x16x64_i8(W[1][c], bf, acc[1], 0, 0, 0);
            }
        }
    };

    // desync: co-resident blocks (ids ~256 apart) anti-phase their barriers
    if ((blockIdx.x >> 8) & 1) {
        __builtin_amdgcn_s_sleep(15);
        __builtin_amdgcn_s_sleep(15);
    }

    // ===== t = 0 (peeled): ec3=0 -> sigmoid = 0.5 exactly; ca1 row-independent =====
    {
        #pragma unroll
        for (int mt = 0; mt < 2; ++mt) {
            const int f0 = wb + mt * 16 + quad * 4;
            const f32x4 av = *(const f32x4*)&Atab[f0];
            const f32x4 ev = *(const f32x4*)&Etab[f0];
            unsigned dw = 0;
            #pragma unroll
            for (int r = 0; r < 4; ++r)
                dw = PKU8(fmaxf(fmaf(av[r], 0.5f, ev[r]), 0.0f), r, dw);
            *(unsigned*)&sStage[4096 + wr[mt]] = dw;   // q(ca1_0)
        }
        __syncthreads();
        const float f2 = ctab[0] * sWc127;
        i32x4 acc2[2];
        gemm(4096, WC, acc2);
        #pragma unroll
        for (int mt = 0; mt < 2; ++mt) {
            const f32x4 cv = *(const f32x4*)&cue[(row0 + L) * 256 + wb + mt * 16 + quad * 4];
            unsigned dw = 0;
            #pragma unroll
            for (int r = 0; r < 4; ++r) {
                const float n5 = __builtin_amdgcn_fmed3f(
                    fmaf((float)acc2[mt][r], f2, e5[mt][r]), 0.0f, 1.0f);
                const float n3 = __builtin_amdgcn_fmed3f(cv[r], 0.0f, 1.0f);  // ec3_prev=0
                e5[mt][r] = n5; e3[mt][r] = n3;
                dw = PKU8(fmaf(n3, 127.0f, 0.5f), r, dw);
            }
            *(unsigned*)&sStage[wr[mt]] = dw;   // q(ec3)
        }
        __syncthreads();
    }

    // ===== steady state t = 1..98: 2 phases, 2 barriers, unroll x2 =====
    #pragma unroll 2
    for (int t = 1; t <= 98; ++t) {
        f32x4 avc[2], evc[2];
        #pragma unroll
        for (int mt = 0; mt < 2; ++mt) {
            const int f0 = t * 256 + wb + mt * 16 + quad * 4;
            avc[mt] = *(const f32x4*)&Atab[f0];
            evc[mt] = *(const f32x4*)&Etab[f0];
        }
        const float f2 = ctab[t] * sWc127;

        // Phase A: G1 (sE -> acc) + e1 (-> sC)
        i32x4 acc[2];
        gemm(0, WA, acc);
        #pragma unroll
        for (int mt = 0; mt < 2; ++mt) {
            unsigned dw = 0;
            #pragma unroll
            for (int r = 0; r < 4; ++r) {
                const float s = __builtin_amdgcn_rcpf(1.0f + __expf((float)acc[mt][r] * nf1));
                const float v = fmaxf(fmaf(avc[mt][r], s, evc[mt][r]), 0.0f);
                dw = PKU8(v, r, dw);
            }
            *(unsigned*)&sStage[4096 + wr[mt]] = dw;
        }
        __syncthreads();

        // Phase B: G2 (sC -> acc2) + e2 (-> sE, state update)
        i32x4 acc2[2];
        gemm(4096, WC, acc2);
        #pragma unroll
        for (int mt = 0; mt < 2; ++mt) {
            unsigned dw = 0;
            #pragma unroll
            for (int r = 0; r < 4; ++r) {
                const float n5 = __builtin_amdgcn_fmed3f(
                    fmaf((float)acc2[mt][r], f2, e5[mt][r]), 0.0f, 1.0f);
                const float n3 = n5 * e3[mt][r];   // both in [0,1]: clip redundant
                e5[mt][r] = n5; e3[mt][r] = n3;
                dw = PKU8(fmaf(n3, 127.0f, 0.5f), r, dw);
            }
            *(unsigned*)&sStage[wr[mt]] = dw;
        }
        __syncthreads();
    }

    // ===== t = 99 (peeled): G1 + e1 + Waction partial dot =====
    {
        i32x4 acc[2];
        gemm(0, WA, acc);
        const float ct = ctab[99];
        float p0 = 0.f, p1 = 0.f;
        #pragma unroll
        for (int mt = 0; mt < 2; ++mt) {
            const int f0 = wb + mt * 16 + quad * 4;
            const f32x4 av = *(const f32x4*)&Atab[99 * 256 + f0];
            const f32x4 ev = *(const f32x4*)&Etab[99 * 256 + f0];
            const f32x4 w0 = *(const f32x4*)&Wact[f0 * 2];       // feats f0, f0+1
            const f32x4 w1 = *(const f32x4*)&Wact[f0 * 2 + 4];   // feats f0+2, f0+3
            #pragma unroll
            for (int r = 0; r < 4; ++r) {
                const float s = __builtin_amdgcn_rcpf(1.0f + __expf((float)acc[mt][r] * nf1));
                const float c = fmaxf(fmaf(av[r], s, ev[r]) - 0.5f, 0.0f) * ct;
                const float wa = (r & 2) ? ((r & 1) ? w1[2] : w1[0]) : ((r & 1) ? w0[2] : w0[0]);
                const float wb2 = (r & 2) ? ((r & 1) ? w1[3] : w1[1]) : ((r & 1) ? w0[3] : w0[1]);
                p0 = fmaf(c, wa, p0);
                p1 = fmaf(c, wb2, p1);
            }
        }
        p0 += __shfl_xor(p0, 16); p0 += __shfl_xor(p0, 32);
        p1 += __shfl_xor(p1, 16); p1 += __shfl_xor(p1, 32);
        if (quad == 0) {
            sPart[(L * 2 + 0) * 8 + wave] = p0;
            sPart[(L * 2 + 1) * 8 + wave] = p1;
        }
    }
    __syncthreads();
    if (tid < 32) {
        float s = 0.f;
        #pragma unroll
        for (int g = 0; g < 8; ++g) s += sPart[tid * 8 + g];
        out[row0 * 2 + tid] = s;
    }
}

extern "C" void kernel_launch(void* const* d_in, const int* in_sizes, int n_in,
                              void* d_out, int out_size, void* d_ws, size_t ws_size,
                              hipStream_t stream) {
    const float* cue      = (const float*)d_in[0];
    const float* ec5_init = (const float*)d_in[1];
    const float* Wapical  = (const float*)d_in[2];
    const float* Wbasal   = (const float*)d_in[3];
    const float* Wca1ec5  = (const float*)d_in[4];
    const float* Waction  = (const float*)d_in[5];
    const float* ca1bias  = (const float*)d_in[6];
    float* out = (float*)d_out;

    float* Atab = (float*)d_ws;                  // 25600 f32
    float* Etab = Atab + 25600;                  // 25600 f32
    float* ctab = Etab + 25600;                  // 100 f32
    int*   scaleWS = (int*)(ctab + 100);         // 4 ints
    char*  qWap = (char*)(scaleWS + 4);          // 65536 B
    char*  qWc  = qWap + 65536;                  // 65536 B

    basal2_kernel<<<100, 256, 0, stream>>>(Wbasal, ca1bias, Atab, Etab, ctab, scaleWS);
    wmax_kernel<<<256, 256, 0, stream>>>(Wapical, Wca1ec5, scaleWS);
    wquant_kernel<<<256, 256, 0, stream>>>(Wapical, Wca1ec5, scaleWS, qWap, qWc);
    rnn_kernel<<<2048, 512, 0, stream>>>(cue, ec5_init, qWap, qWc, scaleWS, Waction,
                                         Atab, Etab, ctab, out);
}